// Round 8
// baseline (8777.152 us; speedup 1.0000x reference)
//
#include <hip/hip_runtime.h>
#include <cmath>

#define BN 2048
#define DXC 256
#define DZC 64
#define INV_B (1.0f/2048.0f)
#define NITER 50

typedef unsigned short ushortT;
typedef __attribute__((ext_vector_type(8))) short s8;
typedef __attribute__((ext_vector_type(4))) float f4;

// ---- workspace layout (float offsets), total ~16.1 MB ----
#define OFF_UT   ((size_t)0)        // f32[256][2048] U^T atomic accumulator
#define OFF_XT   ((size_t)524288)   // f32[256][2048]
#define OFF_KB   ((size_t)1048576)  // ushort Kb[j][i]
#define OFF_WF   ((size_t)3145728)  // f32[128][260] W atomic accumulator (cols 256/257 = a6/a7)
#define OFF_XB   ((size_t)3179008)  // ushort[2048][256]
#define OFF_XRT  ((size_t)3441152)  // ushort[256][2048] r-weighted X^T
#define OFF_VB   ((size_t)3703296)  // ushort[2048][64]
#define OFF_ZB   ((size_t)3768832)  // ushort[2048][64]
#define OFF_ZTB  ((size_t)3834368)  // ushort[128][2048] (row 64=1.0, 65=sqz, 66..127=0)
#define OFF_V64  ((size_t)3965440)
#define OFF_V65  ((size_t)3967488)
#define OFF_SQX  ((size_t)3969536)
#define OFF_SQZ  ((size_t)3971584)
#define OFF_CX   ((size_t)3973632)
#define OFF_CZ   ((size_t)3975680)
#define OFF_R    ((size_t)3977728)  // f32[2][2048] double-buffered r
#define OFF_C    ((size_t)3981824)
#define OFF_RSQX ((size_t)3983872)
#define OFF_RSQZ ((size_t)3985920)
#define OFF_U6   ((size_t)3987968)
#define OFF_U7   ((size_t)3990016)
#define OFF_ACC  ((size_t)3992064)  // f32[5][4][2048] round accumulators
#define OFF_RMX  ((size_t)4033024)
#define OFF_SCAL ((size_t)4035072)
// scal: 0=sum Craw_x, 1=sum Craw_z, 2=sx, 3=sz, 4=sum constx, 5=sum constz,
//       6=cross_term, 7=reg_sum, 8=sum sqx

__device__ __forceinline__ float wave_sum(float v){
  for (int o=32;o;o>>=1) v += __shfl_down(v,o);
  return v;
}
__device__ __forceinline__ void fma16(float (&acc)[4][4], const float* a4, const float* b4){
  #pragma unroll
  for (int m=0;m<4;m++)
    #pragma unroll
    for (int n=0;n<4;n++)
      acc[m][n] = fmaf(a4[m], b4[n], acc[m][n]);
}
__device__ __forceinline__ unsigned encf(float f){
  unsigned u = __float_as_uint(f);
  return (u & 0x80000000u) ? ~u : (u | 0x80000000u);
}
__device__ __forceinline__ float decf(unsigned u){
  return (u & 0x80000000u) ? __uint_as_float(u & 0x7fffffffu) : __uint_as_float(~u);
}
__device__ __forceinline__ ushortT f2bf(float f){
  unsigned u = __float_as_uint(f);
  return (ushortT)((u + 0x7FFFu + ((u>>16)&1u)) >> 16);
}
__device__ __forceinline__ float bf2f(ushortT v){
  return __uint_as_float(((unsigned)v)<<16);
}
__device__ __forceinline__ void gload16(const void* g, void* l){
  __builtin_amdgcn_global_load_lds((const __attribute__((address_space(1))) void*)g,
                                   (__attribute__((address_space(3))) void*)l, 16, 0, 0);
}

// ---------------- MFMA core: 128x128 tile (4 waves), A[M][K] bf16, BT[N][K] bf16 ----
__device__ __forceinline__ void gemm_core(const ushortT* __restrict__ A, int ldA,
                                          const ushortT* __restrict__ B, int ldB,
                                          int m0, int n0, int kstart, int ksteps,
                                          ushortT* As, ushortT* Bs, f4 (&acc)[4][4]){
  const int t = threadIdx.x, w = t>>6, lane = t&63;
  const int wr = w>>1, wc = w&1;
  const int lrow = lane&15, quad = lane>>4;
  const int r0 = w*32;
  const int srow = lane>>3, schunk = (lane&7)*8;
  for (int ks = 0; ks < ksteps; ks++){
    const int kk0 = kstart + ks*64;
    __syncthreads();
    #pragma unroll
    for (int q=0;q<4;q++)
      gload16(A + (size_t)(m0 + r0 + q*8 + srow)*ldA + kk0 + schunk, As + (r0 + q*8)*64);
    #pragma unroll
    for (int q=0;q<4;q++)
      gload16(B + (size_t)(n0 + r0 + q*8 + srow)*ldB + kk0 + schunk, Bs + (r0 + q*8)*64);
    __syncthreads();
    #pragma unroll
    for (int kk=0;kk<2;kk++){
      s8 af[4], bfr[4];
      #pragma unroll
      for (int tm=0;tm<4;tm++)
        af[tm] = *(const s8*)(As + (wr*64 + tm*16 + lrow)*64 + kk*32 + quad*8);
      #pragma unroll
      for (int tn=0;tn<4;tn++)
        bfr[tn] = *(const s8*)(Bs + (wc*64 + tn*16 + lrow)*64 + kk*32 + quad*8);
      #pragma unroll
      for (int tm=0;tm<4;tm++)
        #pragma unroll
        for (int tn=0;tn<4;tn++)
          acc[tm][tn] = __builtin_amdgcn_mfma_f32_16x16x32_bf16(af[tm], bfr[tn], acc[tm][tn], 0,0,0);
    }
  }
}

// ---------------- setup kernels ----------------

__global__ __launch_bounds__(256) void k_zero(float* __restrict__ ws){
  int t = blockIdx.x*256 + threadIdx.x;
  if (t < BN) { ws[OFF_RSQX + t] = 0.f; ws[OFF_RSQZ + t] = 0.f; }
  if (t < 64) ws[OFF_SCAL + t] = 0.f;
}

__global__ __launch_bounds__(64) void k_sq_x(const float* __restrict__ x, float* __restrict__ ws){
  int row = blockIdx.x, t = threadIdx.x;
  const float* xr = x + (size_t)row*DXC;
  float s = 0.f;
  for (int k = t; k < DXC; k += 64) { float v = xr[k]; s += v*v; }
  s = wave_sum(s);
  if (t == 0) { ws[OFF_SQX + row] = s; atomicAdd(&ws[OFF_SCAL+8], s); }
}

__global__ __launch_bounds__(64) void k_sq_z(const float* __restrict__ z, float* __restrict__ ws){
  int row = blockIdx.x, t = threadIdx.x;
  float v = (t < DZC) ? z[(size_t)row*DZC + t] : 0.f;
  float s = wave_sum(v*v);
  if (t == 0) ws[OFF_SQZ + row] = s;
}

template<int D>
__global__ __launch_bounds__(64) void k_stats(const float* __restrict__ P,
                                              const float* __restrict__ sq,
                                              float* __restrict__ ws, int sumidx,
                                              float* __restrict__ rowsq){
  __shared__ __align__(16) float As[32][36];
  __shared__ __align__(16) float Bs[32][36];
  const int i0 = blockIdx.x*32, j0 = blockIdx.y*32;
  const int t = threadIdx.x, tr = t&7, tc = t>>3;
  float acc[4][4] = {};
  for (int k0 = 0; k0 < D; k0 += 32) {
    for (int l = t; l < 1024; l += 64) {
      const int rr = l>>5, cc = l&31;
      As[cc][rr] = P[(size_t)(i0+rr)*D + (k0+cc)];
      Bs[cc][rr] = P[(size_t)(j0+rr)*D + (k0+cc)];
    }
    __syncthreads();
    #pragma unroll
    for (int kk = 0; kk < 32; kk++) {
      float a[4], b[4];
      *(float4*)a = *(const float4*)&As[kk][tr*4];
      *(float4*)b = *(const float4*)&Bs[kk][tc*4];
      fma16(acc, a, b);
    }
    __syncthreads();
  }
  float sqi[4], sqj[4];
  #pragma unroll
  for (int m=0;m<4;m++) sqi[m] = sq[i0+tr*4+m];
  #pragma unroll
  for (int n=0;n<4;n++) sqj[n] = sq[j0+tc*4+n];
  float tot = 0.f; float rs[4] = {0.f,0.f,0.f,0.f};
  #pragma unroll
  for (int m=0;m<4;m++)
    #pragma unroll
    for (int n=0;n<4;n++) {
      float raw = sqi[m] + sqj[n] - 2.f*acc[m][n];
      float cr = fmaxf(raw, 0.f);
      tot += cr;
      rs[m] += cr*cr;
    }
  float v = wave_sum(tot);
  if (t==0) atomicAdd(&ws[OFF_SCAL+sumidx], v);
  #pragma unroll
  for (int m=0;m<4;m++){
    float x2 = rs[m];
    x2 += __shfl_down(x2,32); x2 += __shfl_down(x2,16); x2 += __shfl_down(x2,8);
    if (tc==0) atomicAdd(&rowsq[i0+tr*4+m], x2);
  }
}

__global__ __launch_bounds__(256) void k_s3(const float* __restrict__ z, float* __restrict__ ws){
  int j = blockIdx.x*256 + threadIdx.x;
  float mx = ws[OFF_SCAL+0] / ((float)BN*(float)BN);
  float sx = 1.f/(mx + 1e-8f);
  float mz = ws[OFF_SCAL+1] / ((float)BN*(float)BN);
  float sz = 1.f/(mz + 1e-8f);
  if (j == 0) { ws[OFF_SCAL+2] = sx; ws[OFF_SCAL+3] = sz; }
  if (j < BN) {
    float cx = ws[OFF_RSQX+j]*sx*sx*INV_B;
    float cz = ws[OFF_RSQZ+j]*sz*sz*INV_B;
    ws[OFF_CX+j] = cx; ws[OFF_CZ+j] = cz;
    atomicAdd(&ws[OFF_SCAL+4], cx);
    atomicAdd(&ws[OFF_SCAL+5], cz);
    ws[OFF_R+j] = INV_B; ws[OFF_C+j] = 1.f;
    float msx = ws[OFF_SCAL+8]*INV_B;
    ws[OFF_U6+j] = 1.f;
    ws[OFF_U7+j] = msx;
    ushortT* zb  = (ushortT*)(ws + OFF_ZB);
    ushortT* zTb = (ushortT*)(ws + OFF_ZTB);
    for (int m=0;m<DZC;m++){
      ushortT v = f2bf(z[(size_t)j*DZC + m]);
      zb[(size_t)j*DZC + m] = v;
      zTb[(size_t)m*BN + j] = v;
    }
    zTb[(size_t)64*BN + j] = 0x3F80;               // 1.0
    zTb[(size_t)65*BN + j] = f2bf(ws[OFF_SQZ+j]);  // sqz
    for (int m=66;m<128;m++) zTb[(size_t)m*BN + j] = 0;
  }
}

__global__ __launch_bounds__(256) void k_cvt_x(const float* __restrict__ x, float* __restrict__ ws){
  int idx = blockIdx.x*256 + threadIdx.x;
  ((ushortT*)(ws + OFF_XB))[idx] = f2bf(x[idx]);
}

__global__ __launch_bounds__(256) void k_fillKb(float* __restrict__ ws){
  size_t idx = (size_t)blockIdx.x*256 + threadIdx.x;
  uint4 v = {0x3F803F80u, 0x3F803F80u, 0x3F803F80u, 0x3F803F80u};
  ((uint4*)(ws + OFF_KB))[idx] = v;
}

// XT[k][i] = x[i][k] (f32 transpose, once)
__global__ __launch_bounds__(256) void k_xt(const float* __restrict__ x, float* __restrict__ ws){
  __shared__ float tr[32][65];
  const int i0 = blockIdx.x*64, k0 = blockIdx.y*32;
  const int t = threadIdx.x;
  #pragma unroll
  for (int s=0;s<8;s++){
    int idx = t + s*256; int il = idx>>5, kl = idx&31;
    tr[kl][il] = x[(size_t)(i0+il)*DXC + k0+kl];
  }
  __syncthreads();
  float* XT = ws + OFF_XT;
  #pragma unroll
  for (int s=0;s<8;s++){
    int idx = t + s*256; int kl = idx>>6, il = idx&63;
    XT[(size_t)(k0+kl)*BN + i0+il] = tr[kl][il];
  }
}

// initial xrbT = bf16(XT*INV_B); zero UT/WF/ACC/RMX
__global__ __launch_bounds__(256) void k_xr0(float* __restrict__ ws){
  int idx = blockIdx.x*256 + threadIdx.x;     // grid 2048*256 = 524288
  ((ushortT*)(ws + OFF_XRT))[idx] = f2bf(ws[OFF_XT + idx] * INV_B);
  ws[OFF_UT + idx] = 0.f;
  if (idx < 33280) ws[OFF_WF + idx] = 0.f;
  if (idx < 40960) ws[OFF_ACC + idx] = 0.f;
  if (idx < BN) ((unsigned*)(ws + OFF_RMX))[idx] = 0u;
}

// ---------------- per-iteration kernels ----------------

// k1: atomicAdd f32 into UT[k][j] = sum_i xrbT[k,i]*Kb[j,i]   (grid 2x16x8)
__global__ __launch_bounds__(256) void k1_mfma(float* __restrict__ ws){
  __shared__ __align__(16) ushortT As[128*64];
  __shared__ __align__(16) ushortT Bs[128*64];
  const int m0 = blockIdx.x*128, n0 = blockIdx.y*128, sp = blockIdx.z;
  f4 acc[4][4] = {};
  gemm_core((const ushortT*)(ws+OFF_XRT), BN, (const ushortT*)(ws+OFF_KB), BN,
            m0, n0, sp*256, 4, As, Bs, acc);
  float* __restrict__ UT = ws + OFF_UT;
  const int t = threadIdx.x, w = t>>6, lane = t&63;
  const int wr = w>>1, wc = w&1, lrow = lane&15, quad = lane>>4;
  #pragma unroll
  for (int tm=0;tm<4;tm++)
    #pragma unroll
    for (int tn=0;tn<4;tn++)
      #pragma unroll
      for (int rg=0;rg<4;rg++)
        atomicAdd(&UT[(size_t)(m0+wr*64+tm*16+quad*4+rg)*BN + n0+wc*64+tn*16+lrow],
                  acc[tm][tn][rg]);
}

// kW: Wf[m][kc] += sum_{j in split} zTb[m,j] * stage(kc,j)   (grid 1x3x16)
// stage(kc,j) = kc<256 ? UT[kc][j]*C[j] : kc==256 ? U6[j] : kc==257 ? U7[j] : 0
__global__ __launch_bounds__(256) void kW_mfma(float* __restrict__ ws){
  __shared__ __align__(16) ushortT As[128*64];
  __shared__ __align__(16) ushortT Bs[128*64];
  const int n0 = blockIdx.y*128, sp = blockIdx.z;
  const int t = threadIdx.x, w = t>>6, lane = t&63;
  const int wr = w>>1, wc = w&1, lrow = lane&15, quad = lane>>4;
  const int r0 = w*32, srow = lane>>3, schunk = (lane&7)*8;
  const ushortT* __restrict__ zTb = (const ushortT*)(ws + OFF_ZTB);
  f4 acc[4][4] = {};
  for (int ks = 0; ks < 2; ks++){
    const int kk0 = sp*128 + ks*64;
    __syncthreads();
    #pragma unroll
    for (int q=0;q<4;q++)
      gload16(zTb + (size_t)(r0 + q*8 + srow)*BN + kk0 + schunk, As + (r0 + q*8)*64);
    for (int e = t; e < 8192; e += 256){
      int row = e>>6, col = e&63;
      int kc = n0 + row, j = kk0 + col;
      float val;
      if (kc < 256)       val = ws[OFF_UT + (size_t)kc*BN + j] * ws[OFF_C + j];
      else if (kc == 256) val = ws[OFF_U6 + j];
      else if (kc == 257) val = ws[OFF_U7 + j];
      else                val = 0.f;
      Bs[e] = f2bf(val);
    }
    __syncthreads();
    #pragma unroll
    for (int kk=0;kk<2;kk++){
      s8 af[4], bfr[4];
      #pragma unroll
      for (int tm=0;tm<4;tm++)
        af[tm] = *(const s8*)(As + (wr*64 + tm*16 + lrow)*64 + kk*32 + quad*8);
      #pragma unroll
      for (int tn=0;tn<4;tn++)
        bfr[tn] = *(const s8*)(Bs + (wc*64 + tn*16 + lrow)*64 + kk*32 + quad*8);
      #pragma unroll
      for (int tm=0;tm<4;tm++)
        #pragma unroll
        for (int tn=0;tn<4;tn++)
          acc[tm][tn] = __builtin_amdgcn_mfma_f32_16x16x32_bf16(af[tm], bfr[tn], acc[tm][tn], 0,0,0);
    }
  }
  float* __restrict__ Wf = ws + OFF_WF;
  #pragma unroll
  for (int tn=0;tn<4;tn++){
    const int kc = n0 + wc*64 + tn*16 + lrow;
    if (kc < 258)
      #pragma unroll
      for (int tm=0;tm<4;tm++)
        #pragma unroll
        for (int rg=0;rg<4;rg++)
          atomicAdd(&Wf[(size_t)(wr*64+tm*16+quad*4+rg)*260 + kc], acc[tm][tn][rg]);
  }
}

// kV: V[i][m] = sx*(sqx_i*A6[m] + A7[m] - 2*sum_k xb[i,k]*W[m,k]); B LDS-resident (grid 16)
__global__ __launch_bounds__(256) void kV_mfma(float* __restrict__ ws){
  extern __shared__ __align__(16) char dsm[];
  ushortT* Bsf = (ushortT*)dsm;                        // [128][264] bf16
  ushortT* As  = (ushortT*)(dsm + 128*264*2);          // [128][64]
  float*   A6s = (float*)(dsm + 128*264*2 + 16384);    // [128]
  float*   A7s = A6s + 128;
  const int m0 = blockIdx.x*128;
  const int t = threadIdx.x, w = t>>6, lane = t&63;
  const int wr = w>>1, wc = w&1, lrow = lane&15, quad = lane>>4;
  const int r0 = w*32, srow = lane>>3, schunk = (lane&7)*8;
  // prologue: Wf f32 -> LDS bf16
  for (int e4 = t*4; e4 < 32768; e4 += 1024){
    int m = e4>>8, k = e4&255;
    float4 v4 = *(const float4*)&ws[OFF_WF + (size_t)m*260 + k];
    unsigned lo = f2bf(v4.x) | ((unsigned)f2bf(v4.y)<<16);
    unsigned hi = f2bf(v4.z) | ((unsigned)f2bf(v4.w)<<16);
    *(uint2*)(Bsf + (size_t)m*264 + k) = make_uint2(lo, hi);
  }
  if (t < 128){ A6s[t] = ws[OFF_WF + (size_t)t*260 + 256]; A7s[t] = ws[OFF_WF + (size_t)t*260 + 257]; }
  const ushortT* __restrict__ XB = (const ushortT*)(ws + OFF_XB);
  f4 acc[4][4] = {};
  for (int ks = 0; ks < 4; ks++){
    const int kk0 = ks*64;
    __syncthreads();
    #pragma unroll
    for (int q=0;q<4;q++)
      gload16(XB + (size_t)(m0 + r0 + q*8 + srow)*DXC + kk0 + schunk, As + (r0 + q*8)*64);
    __syncthreads();
    #pragma unroll
    for (int kk=0;kk<2;kk++){
      s8 af[4], bfr[4];
      #pragma unroll
      for (int tm=0;tm<4;tm++)
        af[tm] = *(const s8*)(As + (wr*64 + tm*16 + lrow)*64 + kk*32 + quad*8);
      #pragma unroll
      for (int tn=0;tn<4;tn++)
        bfr[tn] = *(const s8*)(Bsf + (size_t)(wc*64 + tn*16 + lrow)*264 + kk0 + kk*32 + quad*8);
      #pragma unroll
      for (int tm=0;tm<4;tm++)
        #pragma unroll
        for (int tn=0;tn<4;tn++)
          acc[tm][tn] = __builtin_amdgcn_mfma_f32_16x16x32_bf16(af[tm], bfr[tn], acc[tm][tn], 0,0,0);
    }
  }
  const float sx = ws[OFF_SCAL+2];
  ushortT* __restrict__ Vb = (ushortT*)(ws + OFF_VB);
  #pragma unroll
  for (int tn=0;tn<4;tn++){
    const int m = wc*64 + tn*16 + lrow;
    if (m < 66){
      const float a6 = A6s[m], a7 = A7s[m];
      #pragma unroll
      for (int tm=0;tm<4;tm++)
        #pragma unroll
        for (int rg=0;rg<4;rg++){
          const int i = m0 + wr*64 + tm*16 + quad*4 + rg;
          float V = sx*(ws[OFF_SQX+i]*a6 + a7 - 2.f*acc[tm][tn][rg]);
          if (m < 64)       Vb[(size_t)i*64 + m] = f2bf(V);
          else if (m == 64) ws[OFF_V64 + i] = V;
          else              ws[OFF_V65 + i] = V;
        }
    }
  }
}

// k4: cross GEMM. mode 0: row-max of expo only. mode 1: final cross_term.
__global__ __launch_bounds__(256) void k4_mfma(float* __restrict__ ws, int final_pass){
  __shared__ __align__(16) ushortT As[128*64];
  __shared__ __align__(16) ushortT Bs[128*64];
  const int m0 = blockIdx.x*128, n0 = blockIdx.y*128;   // m=j, n=i
  f4 acc[4][4] = {};
  gemm_core((const ushortT*)(ws+OFF_ZB), DZC, (const ushortT*)(ws+OFF_VB), DZC,
            m0, n0, 0, 1, As, Bs, acc);
  const float sz = ws[OFF_SCAL+3];
  const int t = threadIdx.x, w = t>>6, lane = t&63;
  const int wr = w>>1, wc = w&1, lrow = lane&15, quad = lane>>4;
  if (!final_pass){
    unsigned* __restrict__ rmx = (unsigned*)(ws + OFF_RMX);
    #pragma unroll
    for (int tn=0;tn<4;tn++){
      const int i = n0 + wc*64 + tn*16 + lrow;
      const float v64 = ws[OFF_V64+i], v65 = ws[OFF_V65+i], cx = ws[OFF_CX+i];
      float mx = -3.4e38f;
      #pragma unroll
      for (int tm=0;tm<4;tm++)
        #pragma unroll
        for (int rg=0;rg<4;rg++){
          const int j = m0 + wr*64 + tm*16 + quad*4 + rg;
          float cross = sz*(v65 + v64*ws[OFF_SQZ+j] - 2.f*acc[tm][tn][rg]);
          float expo = 2.f*cross - cx - ws[OFF_CZ+j];
          mx = fmaxf(mx, expo);
        }
      mx = fmaxf(mx, __shfl_down(mx,32));
      mx = fmaxf(mx, __shfl_down(mx,16));
      if (quad == 0) atomicMax(&rmx[i], encf(mx));
    }
  } else {
    const ushortT* __restrict__ Kb = (const ushortT*)(ws + OFF_KB);
    float s = 0.f;
    #pragma unroll
    for (int tn=0;tn<4;tn++){
      const int i = n0 + wc*64 + tn*16 + lrow;
      const float v64 = ws[OFF_V64+i], v65 = ws[OFF_V65+i], ri = ws[OFF_R+i];
      #pragma unroll
      for (int tm=0;tm<4;tm++)
        #pragma unroll
        for (int rg=0;rg<4;rg++){
          const int j = m0 + wr*64 + tm*16 + quad*4 + rg;
          float cross = sz*(v65 + v64*ws[OFF_SQZ+j] - 2.f*acc[tm][tn][rg]);
          float tij = ri * bf2f(Kb[(size_t)j*BN + i]) * ws[OFF_C+j];
          s += cross*tij;
        }
    }
    s = wave_sum(s);
    if (lane == 0) atomicAdd(&ws[OFF_SCAL+6], s);
  }
}

// k5: recompute cross GEMM, Kb=bf16(exp(expo-M_i)), rowsum atomicAdd -> ACC[0]
__global__ __launch_bounds__(256) void k5_exp(float* __restrict__ ws){
  __shared__ __align__(16) ushortT As[128*64];
  __shared__ __align__(16) ushortT Bs[128*64];
  const int m0 = blockIdx.x*128, n0 = blockIdx.y*128;
  f4 acc[4][4] = {};
  gemm_core((const ushortT*)(ws+OFF_ZB), DZC, (const ushortT*)(ws+OFF_VB), DZC,
            m0, n0, 0, 1, As, Bs, acc);
  const float sz = ws[OFF_SCAL+3];
  const int t = threadIdx.x, w = t>>6, lane = t&63;
  const int wr = w>>1, wc = w&1, lrow = lane&15, quad = lane>>4;
  const int aln = (blockIdx.y*16 + blockIdx.x)&3;
  ushortT* __restrict__ Kb = (ushortT*)(ws + OFF_KB);
  const unsigned* __restrict__ rmx = (const unsigned*)(ws + OFF_RMX);
  #pragma unroll
  for (int tn=0;tn<4;tn++){
    const int i = n0 + wc*64 + tn*16 + lrow;
    const float v64 = ws[OFF_V64+i], v65 = ws[OFF_V65+i], cx = ws[OFF_CX+i];
    const float Mi = decf(rmx[i]);
    float s = 0.f;
    #pragma unroll
    for (int tm=0;tm<4;tm++)
      #pragma unroll
      for (int rg=0;rg<4;rg++){
        const int j = m0 + wr*64 + tm*16 + quad*4 + rg;
        float cross = sz*(v65 + v64*ws[OFF_SQZ+j] - 2.f*acc[tm][tn][rg]);
        float expo = 2.f*cross - cx - ws[OFF_CZ+j];
        ushortT vv = f2bf(__expf(expo - Mi));
        Kb[(size_t)j*BN + i] = vv;
        s += bf2f(vv);
      }
    s += __shfl_down(s,32);
    s += __shfl_down(s,16);
    if (quad == 0) atomicAdd(&ws[OFF_ACC + (size_t)aln*BN + i], s);
  }
}

// k_cr round n (0..4): thread owns 8 contiguous i-cols; block owns 8 Kb rows.
// rv from ACC[n] (+R prev slot); c-update local; n<4: r-partials -> ACC[n+1];
// n==4: C/U6/U7 + XRT row write + R slot0. Each round also zeroes one buffer.
__global__ __launch_bounds__(256) void k_cr(float* __restrict__ ws, int n){
  __shared__ float red1[8*256];
  __shared__ float red2[8*256];
  __shared__ float ccs[8];
  const int bid = blockIdx.x, t = threadIdx.x;
  const int j0 = bid*8, aln = bid&3;
  const int i0 = t*8;
  // ---- zeroing duty ----
  {
    int gid = bid*256 + t;
    if (n == 0){
      if (gid < BN) ((unsigned*)(ws + OFF_RMX))[gid] = 0u;
      if (gid < 4*BN) ws[OFF_ACC + (size_t)4*4*BN + gid] = 0.f;      // ACC[4]
    } else if (n == 1){
      float4 zz = {0.f,0.f,0.f,0.f};
      *(float4*)&ws[OFF_UT + (size_t)gid*8]     = zz;
      *(float4*)&ws[OFF_UT + (size_t)gid*8 + 4] = zz;
      if (gid < 4*BN) ws[OFF_ACC + gid] = 0.f;                       // ACC[0]
    } else if (n == 2){
      if (gid < 33280) ws[OFF_WF + gid] = 0.f;
      if (gid < 4*BN) ws[OFF_ACC + (size_t)1*4*BN + gid] = 0.f;      // ACC[1]
    } else if (n == 3){
      if (gid < 4*BN) ws[OFF_ACC + (size_t)2*4*BN + gid] = 0.f;      // ACC[2]
    } else {
      if (gid < 4*BN) ws[OFF_ACC + (size_t)3*4*BN + gid] = 0.f;      // ACC[3]
    }
  }
  // ---- rv ----
  const float* __restrict__ ACCn = ws + OFF_ACC + (size_t)n*4*BN;
  float rv[8];
  #pragma unroll
  for (int h=0;h<2;h++){
    float4 s4 = *(const float4*)&ACCn[i0 + h*4];
    #pragma unroll
    for (int lnn=1;lnn<4;lnn++){
      float4 p4 = *(const float4*)&ACCn[(size_t)lnn*BN + i0 + h*4];
      s4.x += p4.x; s4.y += p4.y; s4.z += p4.z; s4.w += p4.w;
    }
    float ss[4] = {s4.x, s4.y, s4.z, s4.w};
    #pragma unroll
    for (int q=0;q<4;q++){
      float s0 = ss[q];
      if (n == 0) rv[h*4+q] = INV_B/(s0 + 1e-8f);
      else {
        float rp = ws[OFF_R + (size_t)((n+1)&1)*BN + i0 + h*4 + q];
        rv[h*4+q] = rp*INV_B/(rp*s0 + 1e-8f);
      }
    }
  }
  // ---- load Kb rows (vectorized 16B) ----
  float v[8][8];
  {
    const ushortT* __restrict__ Kbp = (const ushortT*)(ws + OFF_KB);
    #pragma unroll
    for (int jj=0;jj<8;jj++){
      s8 ld = *(const s8*)(Kbp + (size_t)(j0+jj)*BN + i0);
      const ushortT* pp = (const ushortT*)&ld;
      #pragma unroll
      for (int q=0;q<8;q++) v[jj][q] = bf2f(pp[q]);
    }
  }
  const int last = (n == 4);
  float sqx[8];
  if (last){
    #pragma unroll
    for (int h=0;h<2;h++){
      float4 s4 = *(const float4*)&ws[OFF_SQX + i0 + h*4];
      sqx[h*4]=s4.x; sqx[h*4+1]=s4.y; sqx[h*4+2]=s4.z; sqx[h*4+3]=s4.w;
    }
  }
  #pragma unroll
  for (int jj=0;jj<8;jj++){
    float s1 = 0.f, s2 = 0.f;
    #pragma unroll
    for (int q=0;q<8;q++){
      float kv = v[jj][q]*rv[q];
      s1 += kv;
      if (last) s2 += kv*sqx[q];
    }
    red1[jj*256 + t] = s1;
    red2[jj*256 + t] = s2;
  }
  __syncthreads();
  const int g = t>>5, l = t&31;
  float a = 0.f, b = 0.f;
  #pragma unroll
  for (int k=0;k<8;k++) a += red1[g*256 + l + k*32];
  if (last)
    #pragma unroll
    for (int k=0;k<8;k++) b += red2[g*256 + l + k*32];
  #pragma unroll
  for (int o=16;o;o>>=1){
    a += __shfl_xor(a, o);
    if (last) b += __shfl_xor(b, o);
  }
  if (l == 0){
    const int j = j0 + g;
    float cn;
    if (n == 0) cn = INV_B/(a + 1e-8f);
    else { float cj = ws[OFF_C+j]; cn = cj*INV_B/(cj*a + 1e-8f); }
    ws[OFF_C+j] = cn;
    ccs[g] = cn;
    if (last){ ws[OFF_U6+j] = cn*a; ws[OFF_U7+j] = cn*b; }
  }
  __syncthreads();
  if (!last){
    float cl[8];
    #pragma unroll
    for (int jj=0;jj<8;jj++) cl[jj] = ccs[jj];
    const size_t ro = OFF_ACC + (size_t)((n+1)*4 + aln)*BN;
    #pragma unroll
    for (int q=0;q<8;q++){
      float p = 0.f;
      #pragma unroll
      for (int jj=0;jj<8;jj++) p += v[jj][q]*cl[jj];
      atomicAdd(&ws[ro + i0 + q], p);
    }
    if (bid == 0){
      #pragma unroll
      for (int q=0;q<8;q++) ws[OFF_R + (size_t)(n&1)*BN + i0 + q] = rv[q];
    }
  } else {
    ushortT* __restrict__ XRT = (ushortT*)(ws + OFF_XRT) + (size_t)bid*BN;
    ushortT tmp[8];
    #pragma unroll
    for (int h=0;h<2;h++){
      float4 x4 = *(const float4*)&ws[OFF_XT + (size_t)bid*BN + i0 + h*4];
      tmp[h*4]   = f2bf(x4.x*rv[h*4]);
      tmp[h*4+1] = f2bf(x4.y*rv[h*4+1]);
      tmp[h*4+2] = f2bf(x4.z*rv[h*4+2]);
      tmp[h*4+3] = f2bf(x4.w*rv[h*4+3]);
    }
    *(s8*)(XRT + i0) = *(s8*)tmp;
    if (bid == 0){
      #pragma unroll
      for (int q=0;q<8;q++) ws[OFF_R + i0 + q] = rv[q];
    }
  }
}

// ---------------- reg loss + finalize ----------------

__global__ __launch_bounds__(64) void k_reg(const float* __restrict__ z, const float* __restrict__ y,
                                            float* __restrict__ ws){
  __shared__ __align__(16) float As[32][36];
  __shared__ __align__(16) float Bs[32][36];
  const int i0 = blockIdx.x*32, j0 = blockIdx.y*32;
  const int t = threadIdx.x, tr = t&7, tc = t>>3;
  float acc[4][4] = {};
  for (int k0=0; k0<DZC; k0+=32){
    for (int l=t;l<1024;l+=64){
      const int rr=l>>5, cc=l&31;
      As[cc][rr] = z[(size_t)(i0+rr)*DZC + (k0+cc)];
      Bs[cc][rr] = z[(size_t)(j0+rr)*DZC + (k0+cc)];
    }
    __syncthreads();
    #pragma unroll
    for (int kk=0;kk<32;kk++){
      float a[4], b[4];
      *(float4*)a = *(const float4*)&As[kk][tr*4];
      *(float4*)b = *(const float4*)&Bs[kk][tc*4];
      fma16(acc, a, b);
    }
    __syncthreads();
  }
  const float sz = ws[OFF_SCAL+3];
  float sqi[4], yi[4];
  #pragma unroll
  for (int m=0;m<4;m++){ int i=i0+tr*4+m; sqi[m]=ws[OFF_SQZ+i]; yi[m]=y[i]; }
  float sqj[4], yj[4];
  #pragma unroll
  for (int n=0;n<4;n++){ int j=j0+tc*4+n; sqj[n]=ws[OFF_SQZ+j]; yj[n]=y[j]; }
  float s = 0.f;
  #pragma unroll
  for (int m=0;m<4;m++)
    #pragma unroll
    for (int n=0;n<4;n++){
      int i = i0+tr*4+m, j = j0+tc*4+n;
      float raw = sqi[m] + sqj[n] - 2.f*acc[m][n];
      float cz = sz*fmaxf(raw, 0.f);
      float zd = fmaxf(cz, 1e-4f);
      float d = logf(fabsf(yi[m]-yj[n]) + 1e-6f) - logf(zd + 1e-6f);
      if (i != j) s += d*d;
    }
  s = wave_sum(s);
  if (t==0) atomicAdd(&ws[OFF_SCAL+7], s);
}

__global__ void k_finalize(float* __restrict__ ws, float* __restrict__ out){
  float gw = ws[OFF_SCAL+4]*INV_B + ws[OFF_SCAL+5]*INV_B - 2.f*ws[OFF_SCAL+6];
  gw = fmaxf(gw, 0.f);
  float reg = ws[OFF_SCAL+7] / ((float)BN*(float)(BN-1));
  out[0] = gw + reg;
}

// ---------------- host ----------------

extern "C" void kernel_launch(void* const* d_in, const int* in_sizes, int n_in,
                              void* d_out, int out_size, void* d_ws, size_t ws_size,
                              hipStream_t stream){
  (void)in_sizes; (void)n_in; (void)out_size; (void)ws_size;
  const float* x = (const float*)d_in[0];
  const float* z = (const float*)d_in[1];
  const float* y = (const float*)d_in[2];
  float* out = (float*)d_out;
  float* ws = (float*)d_ws;
  const size_t kv_lds = 128*264*2 + 16384 + 1024;   // ~85 KB dynamic LDS for kV

  hipLaunchKernelGGL(k_zero, dim3(8), dim3(256), 0, stream, ws);
  hipLaunchKernelGGL(k_sq_x, dim3(BN), dim3(64), 0, stream, x, ws);
  hipLaunchKernelGGL(k_sq_z, dim3(BN), dim3(64), 0, stream, z, ws);
  hipLaunchKernelGGL(HIP_KERNEL_NAME(k_stats<DXC>), dim3(64,64), dim3(64), 0, stream,
                     x, ws+OFF_SQX, ws, 0, ws+OFF_RSQX);
  hipLaunchKernelGGL(HIP_KERNEL_NAME(k_stats<DZC>), dim3(64,64), dim3(64), 0, stream,
                     z, ws+OFF_SQZ, ws, 1, ws+OFF_RSQZ);
  hipLaunchKernelGGL(k_s3, dim3(8), dim3(256), 0, stream, z, ws);
  hipLaunchKernelGGL(k_cvt_x, dim3(2048), dim3(256), 0, stream, x, ws);
  hipLaunchKernelGGL(k_fillKb, dim3(2048), dim3(256), 0, stream, ws);
  hipLaunchKernelGGL(k_xt, dim3(32,8), dim3(256), 0, stream, x, ws);
  hipLaunchKernelGGL(k_xr0, dim3(2048), dim3(256), 0, stream, ws);

  for (int it = 0; it < NITER; it++){
    hipLaunchKernelGGL(k1_mfma, dim3(2,16,8), dim3(256), 0, stream, ws);
    hipLaunchKernelGGL(kW_mfma, dim3(1,3,16), dim3(256), 0, stream, ws);
    hipLaunchKernelGGL(kV_mfma, dim3(16), dim3(256), kv_lds, stream, ws);
    hipLaunchKernelGGL(k4_mfma, dim3(16,16), dim3(256), 0, stream, ws, 0);
    hipLaunchKernelGGL(k5_exp, dim3(16,16), dim3(256), 0, stream, ws);
    for (int n = 0; n < 5; n++)
      hipLaunchKernelGGL(k_cr, dim3(256), dim3(256), 0, stream, ws, n);
  }

  // final evaluation with converged T = diag(r) Kb diag(c)
  hipLaunchKernelGGL(k1_mfma, dim3(2,16,8), dim3(256), 0, stream, ws);
  hipLaunchKernelGGL(kW_mfma, dim3(1,3,16), dim3(256), 0, stream, ws);
  hipLaunchKernelGGL(kV_mfma, dim3(16), dim3(256), kv_lds, stream, ws);
  hipLaunchKernelGGL(k4_mfma, dim3(16,16), dim3(256), 0, stream, ws, 1);

  hipLaunchKernelGGL(k_reg, dim3(64,64), dim3(64), 0, stream, z, y, ws);
  hipLaunchKernelGGL(k_finalize, dim3(1), dim3(1), 0, stream, ws, out);
}